// Round 2
// baseline (218.905 us; speedup 1.0000x reference)
//
#include <hip/hip_runtime.h>
#include <hip/hip_bf16.h>

// Problem: T=1024, J=128, B=32, D=256. fp32 in/out (per reference), bf16 MFMA internally.
#define T_ 1024
#define J_ 128
#define B_ 32
#define D_ 256
#define VERY_NEG (-1e30f)

using u16 = unsigned short;
typedef __bf16 bf16x8 __attribute__((ext_vector_type(8)));
typedef u16 u16x4 __attribute__((ext_vector_type(4)));
typedef float f32x4 __attribute__((ext_vector_type(4)));

__device__ __forceinline__ float bf2f(u16 u) {
  union { unsigned int i; float f; } v; v.i = ((unsigned int)u) << 16; return v.f;
}
__device__ __forceinline__ u16 f2bf(float f) {
  union { float f; unsigned int i; } v; v.f = f;
  unsigned int i = v.i;
  return (u16)((i + 0x7fffu + ((i >> 16) & 1u)) >> 16);
}

// ---------------- kernel 0: q_proj[b,j] = qst[j,b,:]·w_q  (c_proj is fused into k_main)
__global__ __launch_bounds__(256) void k_qproj(const float* __restrict__ qst,
                                               const float* __restrict__ attw,
                                               float* __restrict__ ws_qproj) {
  const int wave = threadIdx.x >> 6, lane = threadIdx.x & 63;
  const int gid = blockIdx.x * 4 + wave;  // [0, B*J)
  const int b = gid >> 7, j = gid & 127;
  const float* src = qst + (size_t)j * (B_ * D_) + b * D_ + lane * 4;
  f32x4 a = *(const f32x4*)src;
  f32x4 w = *(const f32x4*)(attw + D_ + lane * 4);
  float s = a[0] * w[0] + a[1] * w[1] + a[2] * w[2] + a[3] * w[3];
#pragma unroll
  for (int m = 32; m >= 1; m >>= 1) s += __shfl_xor(s, m);
  if (lane == 0) ws_qproj[gid] = s;
}

// ---------------- kernel 1: per (b, 64-row t tile): S, softmax_j, c2q, G parts 0-2, row-max
__global__ __launch_bounds__(256) void k_main(const float* __restrict__ ctx,
                                              const float* __restrict__ qst,
                                              const int* __restrict__ con_lens,
                                              const int* __restrict__ qu_lens,
                                              const float* __restrict__ attw,
                                              const float* __restrict__ ws_qproj,
                                              float* __restrict__ ws_mrow,
                                              float* __restrict__ out) {
  // 48KB static LDS: qt half (32KB bf16) + P (16KB bf16); c2q staging reuses the front.
  __shared__ __align__(16) u16 smem[24576];
  u16* qtl = smem;             // [128][128] swizzled question^T half (bf16)
  u16* plds = smem + 16384;    // per-wave P tiles [4][16][128] swizzled (bf16)
  u16* c2q_l = smem;           // [64][264] bf16 c2q staging (after final barrier)

  const int tid = threadIdx.x;
  const int wave = tid >> 6, lane = tid & 63;
  const int lrow = lane & 15, lgrp = lane >> 4;
  const int b = blockIdx.y;
  const int t0 = blockIdx.x * 64;
  const int t0w = t0 + wave * 16;
  const int con = con_lens[b], qu = qu_lens[b];

  // ---- matmul1: cross[t,j] = (ctx*w_cq) @ qst^T; fused c_proj = ctx·w_c
  f32x4 accS[8];
#pragma unroll
  for (int jb = 0; jb < 8; ++jb) accS[jb] = f32x4{0.f, 0.f, 0.f, 0.f};

  float cpr = 0.f;
  const float* rowAp = ctx + (size_t)(t0w + lrow) * (B_ * D_) + b * D_;
#pragma unroll
  for (int ks = 0; ks < 8; ++ks) {
    const int d0 = ks * 32 + lgrp * 8;
    f32x4 a0 = *(const f32x4*)(rowAp + d0);
    f32x4 a1 = *(const f32x4*)(rowAp + d0 + 4);
    f32x4 wq0 = *(const f32x4*)(attw + 2 * D_ + d0);
    f32x4 wq1 = *(const f32x4*)(attw + 2 * D_ + d0 + 4);
    f32x4 wc0 = *(const f32x4*)(attw + d0);
    f32x4 wc1 = *(const f32x4*)(attw + d0 + 4);
    bf16x8 afrag;
#pragma unroll
    for (int e = 0; e < 4; ++e) {
      afrag[e] = (__bf16)(a0[e] * wq0[e]);
      afrag[4 + e] = (__bf16)(a1[e] * wq1[e]);
      cpr += a0[e] * wc0[e] + a1[e] * wc1[e];
    }
#pragma unroll
    for (int jb = 0; jb < 8; ++jb) {
      const float* rb = qst + (size_t)(jb * 16 + lrow) * (B_ * D_) + b * D_ + d0;
      f32x4 b0 = *(const f32x4*)(rb);
      f32x4 b1 = *(const f32x4*)(rb + 4);
      bf16x8 bfrag;
#pragma unroll
      for (int e = 0; e < 4; ++e) {
        bfrag[e] = (__bf16)b0[e];
        bfrag[4 + e] = (__bf16)b1[e];
      }
      accS[jb] = __builtin_amdgcn_mfma_f32_16x16x32_bf16(afrag, bfrag, accS[jb], 0, 0, 0);
    }
  }
  // finish c_proj for row (t0w + lrow): reduce over lgrp lanes (bits 4,5)
  cpr += __shfl_xor(cpr, 16);
  cpr += __shfl_xor(cpr, 32);

  // ---- finalize S, mask, softmax over j. C-layout: col=lane&15, row=(lane>>4)*4+r [m89]
  float cp[4];
#pragma unroll
  for (int r = 0; r < 4; ++r) cp[r] = __shfl(cpr, lgrp * 4 + r);
  float qp[8];
#pragma unroll
  for (int jb = 0; jb < 8; ++jb) qp[jb] = ws_qproj[b * 128 + jb * 16 + lrow];

  float mx[4] = {-3e38f, -3e38f, -3e38f, -3e38f};
#pragma unroll
  for (int jb = 0; jb < 8; ++jb) {
    const int j = jb * 16 + lrow;
#pragma unroll
    for (int r = 0; r < 4; ++r) {
      const int t = t0w + lgrp * 4 + r;
      float s = accS[jb][r] + cp[r] + qp[jb];
      if (t >= con || j >= qu) s += VERY_NEG;
      accS[jb][r] = s;
      mx[r] = fmaxf(mx[r], s);
    }
  }
#pragma unroll
  for (int r = 0; r < 4; ++r) {
    mx[r] = fmaxf(mx[r], __shfl_xor(mx[r], 1));
    mx[r] = fmaxf(mx[r], __shfl_xor(mx[r], 2));
    mx[r] = fmaxf(mx[r], __shfl_xor(mx[r], 4));
    mx[r] = fmaxf(mx[r], __shfl_xor(mx[r], 8));
  }
  if (lrow == 0) {
#pragma unroll
    for (int r = 0; r < 4; ++r) ws_mrow[b * 1024 + t0w + lgrp * 4 + r] = mx[r];
  }
  float sm[4] = {0.f, 0.f, 0.f, 0.f};
#pragma unroll
  for (int jb = 0; jb < 8; ++jb)
#pragma unroll
    for (int r = 0; r < 4; ++r) {
      float p = __expf(accS[jb][r] - mx[r]);
      accS[jb][r] = p;
      sm[r] += p;
    }
#pragma unroll
  for (int r = 0; r < 4; ++r) {
    sm[r] += __shfl_xor(sm[r], 1);
    sm[r] += __shfl_xor(sm[r], 2);
    sm[r] += __shfl_xor(sm[r], 4);
    sm[r] += __shfl_xor(sm[r], 8);
  }

  // ---- P (bf16) -> per-wave LDS, XOR-swizzled: (m,n) at m*128 + ((n>>3 ^ m)<<3) + (n&7)
  {
    u16* pl = plds + wave * 2048;
#pragma unroll
    for (int r = 0; r < 4; ++r) {
      const float inv = 1.0f / sm[r];
      const int m = lgrp * 4 + r;
#pragma unroll
      for (int jb = 0; jb < 8; ++jb) {
        const int n = jb * 16 + lrow;
        pl[m * 128 + (((n >> 3) ^ m) << 3) + (n & 7)] = f2bf(accS[jb][r] * inv);
      }
    }
  }

  // ---- matmul2: c2q = P @ question_bt, question^T staged in LDS in two d-halves
  f32x4 accO[16];
#pragma unroll
  for (int nb = 0; nb < 16; ++nb) accO[nb] = f32x4{0.f, 0.f, 0.f, 0.f};

#pragma unroll
  for (int h = 0; h < 2; ++h) {
    __syncthreads();  // h=1: protect qtl from previous half's readers
    for (int it = 0; it < 8; ++it) {
      const int task = it * 256 + tid;
      const int j = task & 127, dblk = task >> 7;  // dblk 0..15
      const float* qp8 = qst + (size_t)j * (B_ * D_) + b * D_ + h * 128 + dblk * 8;
      f32x4 q0 = *(const f32x4*)(qp8);
      f32x4 q1 = *(const f32x4*)(qp8 + 4);
#pragma unroll
      for (int e = 0; e < 8; ++e) {
        const int dl = dblk * 8 + e;
        const float v = (e < 4) ? q0[e] : q1[e - 4];
        qtl[dl * 128 + (((j >> 3) ^ (dl & 15)) << 3) + (j & 7)] = f2bf(v);
      }
    }
    __syncthreads();
#pragma unroll
    for (int ks2 = 0; ks2 < 4; ++ks2) {
      const int chunkA = ks2 * 4 + lgrp;
      const bf16x8 ap =
          *(const bf16x8*)(plds + wave * 2048 + lrow * 128 + ((chunkA ^ lrow) << 3));
#pragma unroll
      for (int nbl = 0; nbl < 8; ++nbl) {
        const int dl = nbl * 16 + lrow;
        const bf16x8 bq = *(const bf16x8*)(qtl + dl * 128 + ((chunkA ^ (dl & 15)) << 3));
        accO[h * 8 + nbl] =
            __builtin_amdgcn_mfma_f32_16x16x32_bf16(ap, bq, accO[h * 8 + nbl], 0, 0, 0);
      }
    }
  }
  __syncthreads();  // all P/QT reads done; reuse LDS for c2q staging

  // ---- c2q -> LDS (bf16, stride 264)
#pragma unroll
  for (int nb = 0; nb < 16; ++nb)
#pragma unroll
    for (int r = 0; r < 4; ++r) {
      const int row = wave * 16 + lgrp * 4 + r;
      const int d = nb * 16 + lrow;
      c2q_l[row * 264 + d] = f2bf(accO[nb][r]);
    }
  __syncthreads();

  // ---- epilogue: coalesced fp32 writes of G parts 0..2 for 64 rows
  for (int ii = 0; ii < 16; ++ii) {
    const int idx = ii * 256 + tid;           // [0, 4096)
    const int row = idx >> 6, c = idx & 63;   // 64 rows x 64 float4-chunks
    const int t = t0 + row;
    const bool valid = t < con;
    f32x4 cr = *(const f32x4*)(ctx + (size_t)t * (B_ * D_) + b * D_ + c * 4);
    u16x4 cq = *(const u16x4*)(c2q_l + row * 264 + c * 4);
    f32x4 p0, p1, p2;
#pragma unroll
    for (int e = 0; e < 4; ++e) {
      const float cf = valid ? cr[e] : 0.f;
      const float qf = valid ? bf2f(cq[e]) : 0.f;
      p0[e] = cf;
      p1[e] = qf;
      p2[e] = cf * qf;
    }
    float* g = out + ((size_t)(b * 1024 + t)) * 1024 + c * 4;
    *(f32x4*)(g) = p0;
    *(f32x4*)(g + 256) = p1;
    *(f32x4*)(g + 512) = p2;
  }
}

// ---------------- kernel 2: value = softmax_t(max_j S); q2c[b,d] += partial (atomics)
__global__ __launch_bounds__(256) void k_value(const float* __restrict__ ctx,
                                               const float* __restrict__ mrow,
                                               float* __restrict__ q2c) {
  __shared__ float wls[1024];
  __shared__ float red[8];
  const int b = blockIdx.x >> 3, tc = blockIdx.x & 7;  // 8 t-chunks of 128
  const int tid = threadIdx.x;
  const int wave = tid >> 6, lane = tid & 63;
  const float* mr = mrow + b * 1024;

  float mx = -3e38f;
  for (int t = tid; t < 1024; t += 256) mx = fmaxf(mx, mr[t]);
#pragma unroll
  for (int m = 32; m >= 1; m >>= 1) mx = fmaxf(mx, __shfl_xor(mx, m));
  if (lane == 0) red[wave] = mx;
  __syncthreads();
  mx = fmaxf(fmaxf(red[0], red[1]), fmaxf(red[2], red[3]));

  float sl = 0.f;
  for (int t = tid; t < 1024; t += 256) {
    float wv = __expf(mr[t] - mx);
    wls[t] = wv;
    sl += wv;
  }
#pragma unroll
  for (int m = 32; m >= 1; m >>= 1) sl += __shfl_xor(sl, m);
  if (lane == 0) red[4 + wave] = sl;
  __syncthreads();
  const float inv = 1.0f / (red[4] + red[5] + red[6] + red[7]);

  const int d = tid;  // 256 threads == D
  const float* cp = ctx + b * D_ + d;
  const int tb = tc * 128;
  float a0 = 0.f, a1 = 0.f, a2 = 0.f, a3 = 0.f;
  for (int t = tb; t < tb + 128; t += 4) {
    a0 += wls[t + 0] * cp[(size_t)(t + 0) * (B_ * D_)];
    a1 += wls[t + 1] * cp[(size_t)(t + 1) * (B_ * D_)];
    a2 += wls[t + 2] * cp[(size_t)(t + 2) * (B_ * D_)];
    a3 += wls[t + 3] * cp[(size_t)(t + 3) * (B_ * D_)];
  }
  atomicAdd(&q2c[b * D_ + d], (a0 + a1 + a2 + a3) * inv);
}

// ---------------- kernel 3: G part 3 = ctx * q2c (masked)
__global__ __launch_bounds__(256) void k_part3(const float* __restrict__ ctx,
                                               const int* __restrict__ con_lens,
                                               const float* __restrict__ q2c,
                                               float* __restrict__ out) {
  const int idx = blockIdx.x * 256 + threadIdx.x;
  const int c = idx & 63, t = (idx >> 6) & 1023, b = idx >> 16;
  const bool valid = t < con_lens[b];
  f32x4 cr = *(const f32x4*)(ctx + (size_t)t * (B_ * D_) + b * D_ + c * 4);
  const f32x4 qv = *(const f32x4*)(q2c + b * D_ + c * 4);
  f32x4 o;
#pragma unroll
  for (int e = 0; e < 4; ++e) o[e] = valid ? cr[e] * qv[e] : 0.f;
  *(f32x4*)(out + ((size_t)(b * 1024 + t)) * 1024 + 768 + c * 4) = o;
}

extern "C" void kernel_launch(void* const* d_in, const int* in_sizes, int n_in,
                              void* d_out, int out_size, void* d_ws, size_t ws_size,
                              hipStream_t stream) {
  const float* ctx = (const float*)d_in[0];
  const float* qst = (const float*)d_in[1];
  const int* con = (const int*)d_in[2];
  const int* qu = (const int*)d_in[3];
  const float* attw = (const float*)d_in[4];
  float* out = (float*)d_out;

  float* ws = (float*)d_ws;
  float* ws_qproj = ws;          // B*J   =  4096
  float* ws_mrow = ws + 4096;    // B*T   = 32768
  float* ws_q2c = ws + 36864;    // B*D   =  8192   (total 176 KB)

  hipMemsetAsync((void*)ws_q2c, 0, B_ * D_ * sizeof(float), stream);
  k_qproj<<<1024, 256, 0, stream>>>(qst, attw, ws_qproj);
  k_main<<<dim3(16, 32), 256, 0, stream>>>(ctx, qst, con, qu, attw, ws_qproj, ws_mrow,
                                           out);
  k_value<<<256, 256, 0, stream>>>(ctx, ws_mrow, ws_q2c);
  k_part3<<<8192, 256, 0, stream>>>(ctx, con, ws_q2c, out);
}

// Round 3
// 190.653 us; speedup vs baseline: 1.1482x; 1.1482x over previous
//
#include <hip/hip_runtime.h>
#include <hip/hip_bf16.h>

// Problem: T=1024, J=128, B=32, D=256. fp32 in/out (per reference), bf16 MFMA internally.
#define T_ 1024
#define J_ 128
#define B_ 32
#define D_ 256
#define VERY_NEG (-1e30f)

using u16 = unsigned short;
typedef __bf16 bf16x8 __attribute__((ext_vector_type(8)));
typedef u16 u16x8 __attribute__((ext_vector_type(8)));
typedef u16 u16x4 __attribute__((ext_vector_type(4)));
typedef float f32x4 __attribute__((ext_vector_type(4)));

__device__ __forceinline__ float bf2f(u16 u) {
  union { unsigned int i; float f; } v; v.i = ((unsigned int)u) << 16; return v.f;
}
__device__ __forceinline__ u16 f2bf(float f) {
  union { float f; unsigned int i; } v; v.f = f;
  unsigned int i = v.i;
  return (u16)((i + 0x7fffu + ((i >> 16) & 1u)) >> 16);
}

// ---------------- kernel 0: q_proj[b,j] = qst·w_q  AND  qst -> bf16 buffer
__global__ __launch_bounds__(256) void k_prep(const float* __restrict__ qst,
                                              const float* __restrict__ attw,
                                              float* __restrict__ ws_qproj,
                                              u16* __restrict__ ws_qbf) {
  const int wave = threadIdx.x >> 6, lane = threadIdx.x & 63;
  const int gid = blockIdx.x * 4 + wave;  // [0, B*J)
  const int b = gid >> 7, j = gid & 127;
  const size_t off = (size_t)j * (B_ * D_) + b * D_ + lane * 4;
  f32x4 a = *(const f32x4*)(qst + off);
  f32x4 w = *(const f32x4*)(attw + D_ + lane * 4);
  u16x4 qb;
#pragma unroll
  for (int e = 0; e < 4; ++e) qb[e] = f2bf(a[e]);
  *(u16x4*)(ws_qbf + off) = qb;
  float s = a[0] * w[0] + a[1] * w[1] + a[2] * w[2] + a[3] * w[3];
#pragma unroll
  for (int m = 32; m >= 1; m >>= 1) s += __shfl_xor(s, m);
  if (lane == 0) ws_qproj[gid] = s;
}

// ---------------- kernel 1: per (b, 64-row t tile): S, softmax_j, c2q, G parts 0-2,
//                  + fused q2c tile-partials (pnum/pden/Mt)
__global__ __launch_bounds__(256) void k_main(const float* __restrict__ ctx,
                                              const u16* __restrict__ qbf,
                                              const int* __restrict__ con_lens,
                                              const int* __restrict__ qu_lens,
                                              const float* __restrict__ attw,
                                              const float* __restrict__ ws_qproj,
                                              float* __restrict__ ws_mtile,
                                              float* __restrict__ ws_pden,
                                              float* __restrict__ ws_pnum,
                                              float* __restrict__ out) {
  // 48KB: qt half (32KB bf16) + P (16KB bf16); c2q staging (33.8KB) reuses the front;
  // red4 (4KB) overlays bytes 33792.. (free after mm2).
  __shared__ __align__(16) u16 smem[24576];
  __shared__ float mrow_l[64];
  __shared__ float msc[1];
  u16* qtl = smem;             // [128][128] swizzled question^T half (bf16)
  u16* plds = smem + 16384;    // per-wave P tiles [4][16][128] swizzled (bf16)
  u16* c2q_l = smem;           // [64][264] bf16 c2q staging (after final barrier)
  float* red4 = (float*)(smem + 16896);  // [4][64][4] floats, byte 33792..37887

  const int tid = threadIdx.x;
  const int wave = tid >> 6, lane = tid & 63;
  const int lrow = lane & 15, lgrp = lane >> 4;
  const int b = blockIdx.y;
  const int t0 = blockIdx.x * 64;
  const int t0w = t0 + wave * 16;
  const int con = con_lens[b], qu = qu_lens[b];

  // ---- matmul1: cross[t,j] = (ctx*w_cq) @ qst^T; fused c_proj = ctx·w_c
  f32x4 accS[8];
#pragma unroll
  for (int jb = 0; jb < 8; ++jb) accS[jb] = f32x4{0.f, 0.f, 0.f, 0.f};

  float cpr = 0.f;
  const float* rowAp = ctx + (size_t)(t0w + lrow) * (B_ * D_) + b * D_;
#pragma unroll
  for (int ks = 0; ks < 8; ++ks) {
    const int d0 = ks * 32 + lgrp * 8;
    f32x4 a0 = *(const f32x4*)(rowAp + d0);
    f32x4 a1 = *(const f32x4*)(rowAp + d0 + 4);
    f32x4 wq0 = *(const f32x4*)(attw + 2 * D_ + d0);
    f32x4 wq1 = *(const f32x4*)(attw + 2 * D_ + d0 + 4);
    f32x4 wc0 = *(const f32x4*)(attw + d0);
    f32x4 wc1 = *(const f32x4*)(attw + d0 + 4);
    bf16x8 afrag;
#pragma unroll
    for (int e = 0; e < 4; ++e) {
      afrag[e] = (__bf16)(a0[e] * wq0[e]);
      afrag[4 + e] = (__bf16)(a1[e] * wq1[e]);
      cpr += a0[e] * wc0[e] + a1[e] * wc1[e];
    }
#pragma unroll
    for (int jb = 0; jb < 8; ++jb) {
      const bf16x8 bfrag =
          *(const bf16x8*)(qbf + (size_t)(jb * 16 + lrow) * (B_ * D_) + b * D_ + d0);
      accS[jb] = __builtin_amdgcn_mfma_f32_16x16x32_bf16(afrag, bfrag, accS[jb], 0, 0, 0);
    }
  }
  // finish c_proj for row (t0w + lrow): reduce over lgrp lanes (bits 4,5)
  cpr += __shfl_xor(cpr, 16);
  cpr += __shfl_xor(cpr, 32);

  // ---- finalize S, mask, softmax over j. C-layout: col=lane&15, row=(lane>>4)*4+r [m89]
  float cp[4];
#pragma unroll
  for (int r = 0; r < 4; ++r) cp[r] = __shfl(cpr, lgrp * 4 + r);
  float qp[8];
#pragma unroll
  for (int jb = 0; jb < 8; ++jb) qp[jb] = ws_qproj[b * 128 + jb * 16 + lrow];

  float mx[4] = {-3e38f, -3e38f, -3e38f, -3e38f};
#pragma unroll
  for (int jb = 0; jb < 8; ++jb) {
    const int j = jb * 16 + lrow;
#pragma unroll
    for (int r = 0; r < 4; ++r) {
      const int t = t0w + lgrp * 4 + r;
      float s = accS[jb][r] + cp[r] + qp[jb];
      if (t >= con || j >= qu) s += VERY_NEG;
      accS[jb][r] = s;
      mx[r] = fmaxf(mx[r], s);
    }
  }
#pragma unroll
  for (int r = 0; r < 4; ++r) {
    mx[r] = fmaxf(mx[r], __shfl_xor(mx[r], 1));
    mx[r] = fmaxf(mx[r], __shfl_xor(mx[r], 2));
    mx[r] = fmaxf(mx[r], __shfl_xor(mx[r], 4));
    mx[r] = fmaxf(mx[r], __shfl_xor(mx[r], 8));
  }
  if (lrow == 0) {
#pragma unroll
    for (int r = 0; r < 4; ++r) mrow_l[wave * 16 + lgrp * 4 + r] = mx[r];
  }
  float sm[4] = {0.f, 0.f, 0.f, 0.f};
#pragma unroll
  for (int jb = 0; jb < 8; ++jb)
#pragma unroll
    for (int r = 0; r < 4; ++r) {
      float p = __expf(accS[jb][r] - mx[r]);
      accS[jb][r] = p;
      sm[r] += p;
    }
#pragma unroll
  for (int r = 0; r < 4; ++r) {
    sm[r] += __shfl_xor(sm[r], 1);
    sm[r] += __shfl_xor(sm[r], 2);
    sm[r] += __shfl_xor(sm[r], 4);
    sm[r] += __shfl_xor(sm[r], 8);
  }

  // ---- P (bf16) -> per-wave LDS, XOR-swizzled: (m,n) at m*128 + ((n>>3 ^ m)<<3) + (n&7)
  {
    u16* pl = plds + wave * 2048;
#pragma unroll
    for (int r = 0; r < 4; ++r) {
      const float inv = 1.0f / sm[r];
      const int m = lgrp * 4 + r;
#pragma unroll
      for (int jb = 0; jb < 8; ++jb) {
        const int n = jb * 16 + lrow;
        pl[m * 128 + (((n >> 3) ^ m) << 3) + (n & 7)] = f2bf(accS[jb][r] * inv);
      }
    }
  }

  // ---- matmul2: c2q = P @ question_bt, question^T staged in LDS in two d-halves
  f32x4 accO[16];
#pragma unroll
  for (int nb = 0; nb < 16; ++nb) accO[nb] = f32x4{0.f, 0.f, 0.f, 0.f};

#pragma unroll
  for (int h = 0; h < 2; ++h) {
    __syncthreads();  // h=1: protect qtl from previous half's readers
    for (int it = 0; it < 8; ++it) {
      const int task = it * 256 + tid;
      const int j = task & 127, dblk = task >> 7;  // dblk 0..15
      u16x8 q = *(const u16x8*)(qbf + (size_t)j * (B_ * D_) + b * D_ + h * 128 + dblk * 8);
#pragma unroll
      for (int e = 0; e < 8; ++e) {
        const int dl = dblk * 8 + e;
        qtl[dl * 128 + (((j >> 3) ^ (dl & 15)) << 3) + (j & 7)] = q[e];
      }
    }
    __syncthreads();
#pragma unroll
    for (int ks2 = 0; ks2 < 4; ++ks2) {
      const int chunkA = ks2 * 4 + lgrp;
      const bf16x8 ap =
          *(const bf16x8*)(plds + wave * 2048 + lrow * 128 + ((chunkA ^ lrow) << 3));
#pragma unroll
      for (int nbl = 0; nbl < 8; ++nbl) {
        const int dl = nbl * 16 + lrow;
        const bf16x8 bq = *(const bf16x8*)(qtl + dl * 128 + ((chunkA ^ (dl & 15)) << 3));
        accO[h * 8 + nbl] =
            __builtin_amdgcn_mfma_f32_16x16x32_bf16(ap, bq, accO[h * 8 + nbl], 0, 0, 0);
      }
    }
  }
  __syncthreads();  // all P/QT reads done; reuse LDS for c2q staging

  // ---- c2q -> LDS (bf16, stride 264)
#pragma unroll
  for (int nb = 0; nb < 16; ++nb)
#pragma unroll
    for (int r = 0; r < 4; ++r) {
      const int row = wave * 16 + lgrp * 4 + r;
      const int d = nb * 16 + lrow;
      c2q_l[row * 264 + d] = f2bf(accO[nb][r]);
    }
  __syncthreads();

  // ---- tile softmax-combine prep: Mt = max(mrow), mrow_l <- exp(mrow - Mt), pden
  if (tid < 64) {
    float v = mrow_l[tid];
#pragma unroll
    for (int m = 32; m >= 1; m >>= 1) v = fmaxf(v, __shfl_xor(v, m));
    if (tid == 0) msc[0] = v;
  }
  __syncthreads();
  const float Mt = msc[0];
  if (tid < 64) {
    const float mr = mrow_l[tid];
    const float e = (mr < -1e29f) ? 0.f : __expf(mr - Mt);
    mrow_l[tid] = e;
    float s2 = e;
#pragma unroll
    for (int m = 32; m >= 1; m >>= 1) s2 += __shfl_xor(s2, m);
    if (tid == 0) {
      ws_mtile[b * 16 + blockIdx.x] = Mt;
      ws_pden[b * 16 + blockIdx.x] = s2;
    }
  }
  __syncthreads();

  // ---- epilogue: coalesced fp32 writes of G parts 0..2 + q2c weighted partials
  f32x4 acc4 = {0.f, 0.f, 0.f, 0.f};
  const int c = tid & 63;
  for (int ii = 0; ii < 16; ++ii) {
    const int row = ii * 4 + wave;
    const int t = t0 + row;
    const bool valid = t < con;
    f32x4 cr = *(const f32x4*)(ctx + (size_t)t * (B_ * D_) + b * D_ + c * 4);
    u16x4 cq = *(const u16x4*)(c2q_l + row * 264 + c * 4);
    const float w = mrow_l[row];  // exp(mrow - Mt), 0 for invalid rows
    f32x4 p0, p1, p2;
#pragma unroll
    for (int e = 0; e < 4; ++e) {
      const float cf = valid ? cr[e] : 0.f;
      const float qf = valid ? bf2f(cq[e]) : 0.f;
      p0[e] = cf;
      p1[e] = qf;
      p2[e] = cf * qf;
      acc4[e] += w * cr[e];  // raw ctx (reference uses unmasked ctx; w==0 kills invalid)
    }
    float* g = out + ((size_t)(b * 1024 + t)) * 1024 + c * 4;
    *(f32x4*)(g) = p0;
    *(f32x4*)(g + 256) = p1;
    *(f32x4*)(g + 512) = p2;
  }
  *(f32x4*)(red4 + wave * 256 + c * 4) = acc4;
  __syncthreads();
  {
    const float sum = red4[tid] + red4[256 + tid] + red4[512 + tid] + red4[768 + tid];
    ws_pnum[((size_t)b * 16 + blockIdx.x) * 256 + tid] = sum;
  }
}

// ---------------- kernel 2: combine tile partials -> q2c[b][256]
__global__ __launch_bounds__(256) void k_combine(const float* __restrict__ ws_mtile,
                                                 const float* __restrict__ ws_pden,
                                                 const float* __restrict__ ws_pnum,
                                                 float* __restrict__ q2c) {
  __shared__ float se[16];
  __shared__ float sden[1];
  const int b = blockIdx.x, tid = threadIdx.x;
  if (tid < 64) {
    const float mt = (tid < 16) ? ws_mtile[b * 16 + tid] : -3e38f;
    float M = mt;
#pragma unroll
    for (int m = 8; m >= 1; m >>= 1) M = fmaxf(M, __shfl_xor(M, m));
    const float pd = (tid < 16) ? ws_pden[b * 16 + tid] : 0.f;
    const float e = (tid < 16 && mt > -1e29f) ? __expf(mt - M) : 0.f;
    if (tid < 16) se[tid] = e;
    float cden = e * pd;
#pragma unroll
    for (int m = 8; m >= 1; m >>= 1) cden += __shfl_xor(cden, m);
    if (tid == 0) sden[0] = cden;
  }
  __syncthreads();
  const float den = sden[0];
  float num = 0.f;
#pragma unroll
  for (int i = 0; i < 16; ++i) num += se[i] * ws_pnum[((size_t)b * 16 + i) * 256 + tid];
  q2c[b * 256 + tid] = num / den;
}

// ---------------- kernel 3: G part 3 = ctx * q2c (masked)
__global__ __launch_bounds__(256) void k_part3(const float* __restrict__ ctx,
                                               const int* __restrict__ con_lens,
                                               const float* __restrict__ q2c,
                                               float* __restrict__ out) {
  const int idx = blockIdx.x * 256 + threadIdx.x;
  const int c = idx & 63, t = (idx >> 6) & 1023, b = idx >> 16;
  const bool valid = t < con_lens[b];
  f32x4 cr = *(const f32x4*)(ctx + (size_t)t * (B_ * D_) + b * D_ + c * 4);
  const f32x4 qv = *(const f32x4*)(q2c + b * D_ + c * 4);
  f32x4 o;
#pragma unroll
  for (int e = 0; e < 4; ++e) o[e] = valid ? cr[e] * qv[e] : 0.f;
  *(f32x4*)(out + ((size_t)(b * 1024 + t)) * 1024 + 768 + c * 4) = o;
}

extern "C" void kernel_launch(void* const* d_in, const int* in_sizes, int n_in,
                              void* d_out, int out_size, void* d_ws, size_t ws_size,
                              hipStream_t stream) {
  const float* ctx = (const float*)d_in[0];
  const float* qst = (const float*)d_in[1];
  const int* con = (const int*)d_in[2];
  const int* qu = (const int*)d_in[3];
  const float* attw = (const float*)d_in[4];
  float* out = (float*)d_out;

  float* ws = (float*)d_ws;
  float* ws_qproj = ws;                       // 4096 floats
  u16* ws_qbf = (u16*)(ws + 4096);            // 1M u16 (2 MB) = 524288 float slots
  float* ws_mtile = ws + 528384;              // 512
  float* ws_pden = ws + 528896;               // 512
  float* ws_pnum = ws + 529408;               // 131072
  float* ws_q2c = ws + 660480;                // 8192  (total ~2.7 MB)

  k_prep<<<1024, 256, 0, stream>>>(qst, attw, ws_qproj, ws_qbf);
  k_main<<<dim3(16, 32), 256, 0, stream>>>(ctx, ws_qbf, con, qu, attw, ws_qproj,
                                           ws_mtile, ws_pden, ws_pnum, out);
  k_combine<<<32, 256, 0, stream>>>(ws_mtile, ws_pden, ws_pnum, ws_q2c);
  k_part3<<<8192, 256, 0, stream>>>(ctx, con, ws_q2c, out);
}